// Round 7
// baseline (198.685 us; speedup 1.0000x reference)
//
#include <hip/hip_runtime.h>
#include <hip/hip_bf16.h>
#include <math.h>

// Problem constants: B=8, M=256, N=256, I=64, O=64, NM=16
// Workspace float layout:
//   [0)      tabA  [n=256][ky=16][2]        8192   forward-n twiddles (cos,-sin)
//   [8192)   twF   [oc=4][m=256][kl=8][2]  16384   forward-m twiddles (cos,-sin)
//   [24576)  twI   [kx=32][m=256][2]       16384   inverse-m twiddles (cos,+sin)/256
//   [40960)  tabE  [f=32][n=256]            8192   inverse-n basis (scaled cos / -sin)
//   [49152)  Wf    [o'=64][o=64]            4096   I + lin_w
//   [65536)  T     [b=8][ky=16][m=256][i=64][2]   = 4194304
//   [+T]     X     [b=8][ky=16][kx=32][i=64][2]   =  524288
//   [+X]     Y2    [b=8][kx=32][ky=16][o=64][2]   =  524288
//   [+Y2]    G     [b=8][m=256][ky=16][o=64][2]   = 4194304

#define TOFF  65536
#define XOFF  (TOFF + 4194304)
#define YOFF  (XOFF + 524288)
#define GOFF  (YOFF + 524288)

__global__ __launch_bounds__(256) void setup_tables(const float* __restrict__ lin_w,
                                                    float* __restrict__ ws) {
    int j = blockIdx.x * 256 + threadIdx.x;
    const float ANG = 0.024543692606170259f; // 2*pi/256
    if (j < 4096) {                       // tabA [n][ky][2]
        int n = j >> 4, ky = j & 15;
        int a = (n * ky) & 255;
        float s, c; sincosf(ANG * (float)a, &s, &c);
        float* p = ws + n * 32 + ky * 2;
        p[0] = c; p[1] = -s;
    } else if (j < 12288) {               // twF [oc][m][kl=8][2]
        int e = j - 4096; int m = e >> 5, kx = e & 31;
        int kxe = kx + (kx < 16 ? 0 : 224);   // 0..15, 240..255
        int a = (m * kxe) & 255;
        float s, c; sincosf(ANG * (float)a, &s, &c);
        int oc = kx >> 3, kl = kx & 7;
        float* p = ws + 8192 + oc * 4096 + m * 16 + kl * 2;
        p[0] = c; p[1] = -s;
    } else if (j < 20480) {               // twI
        int e = j - 12288; int kx = e >> 8, m = e & 255;
        int kxe = kx + (kx < 16 ? 0 : 224);
        int a = (kxe * m) & 255;
        float s, c; sincosf(ANG * (float)a, &s, &c);
        float* p = ws + 24576 + (kx * 256 + m) * 2;
        p[0] = c * (1.0f / 256.0f);
        p[1] = s * (1.0f / 256.0f);
    } else if (j < 28672) {               // tabE
        int e = j - 20480; int f = e >> 8, n = e & 255;
        int ky = f >> 1, h = f & 1;
        int a = (ky * n) & 255;
        float s, c; sincosf(ANG * (float)a, &s, &c);
        float scale = (ky == 0 ? 1.0f : 2.0f) * (1.0f / 256.0f);
        ws[40960 + f * 256 + n] = h ? (-scale * s) : (scale * c);
    } else if (j < 32768) {               // Wf = I + lin_w
        int e = j - 28672;
        int op = e >> 6, o = e & 63;
        ws[49152 + e] = lin_w[e] + ((op == o) ? 1.0f : 0.0f);
    }
}

// Stage A v8: block=(b,m), 4 waves = ky-quads. Lane l = (su = l>>4, j = l&15):
// handles n === su (mod 4), i-quad 4j..4j+3. ALL loop loads are VMEM dwordx4
// (x: 1KB contiguous per wave-instr; twiddles: L1-resident table) -> single
// in-order vmcnt queue, compiler pipelines. No SMEM/LDS/barriers in loop.
// End: 2x shfl_xor butterfly over su-groups + static-index select, f4 stores.
__global__ __launch_bounds__(256) void stageA(const float* __restrict__ x,
                                              const float* __restrict__ tabA,
                                              float* __restrict__ T) {
    int bid = blockIdx.x;       // b*256 + m
    int b = bid >> 8, m = bid & 255;
    int t = threadIdx.x;
    int kq = t >> 6;            // wave = ky quad
    int l = t & 63;
    int su = l >> 4, j = l & 15;
    const float* xp  = x + (size_t)bid * 16384 + su * 64 + j * 4;
    const float* twp = tabA + su * 32 + kq * 8;
    float accR[4][4], accI[4][4];   // [ii = i-sub][k = ky-sub]
#pragma unroll
    for (int ii = 0; ii < 4; ++ii)
#pragma unroll
        for (int k = 0; k < 4; ++k) { accR[ii][k] = 0.f; accI[ii][k] = 0.f; }

#pragma unroll 4
    for (int n0 = 0; n0 < 256; n0 += 4) {
        float4 xv = *(const float4*)(xp + (size_t)n0 * 64);
        float4 t0 = *(const float4*)(twp + (size_t)n0 * 32);
        float4 t1 = *(const float4*)(twp + (size_t)n0 * 32 + 4);
#define CPLX(K, C, S)                                                       \
        accR[0][K] = fmaf(C, xv.x, accR[0][K]); accI[0][K] = fmaf(S, xv.x, accI[0][K]); \
        accR[1][K] = fmaf(C, xv.y, accR[1][K]); accI[1][K] = fmaf(S, xv.y, accI[1][K]); \
        accR[2][K] = fmaf(C, xv.z, accR[2][K]); accI[2][K] = fmaf(S, xv.z, accI[2][K]); \
        accR[3][K] = fmaf(C, xv.w, accR[3][K]); accI[3][K] = fmaf(S, xv.w, accI[3][K]);
        CPLX(0, t0.x, t0.y)
        CPLX(1, t0.z, t0.w)
        CPLX(2, t1.x, t1.y)
        CPLX(3, t1.z, t1.w)
#undef CPLX
    }
    // butterfly-reduce over the 4 su lanes (l, l^16, l^32, l^48)
#pragma unroll
    for (int ii = 0; ii < 4; ++ii)
#pragma unroll
        for (int k = 0; k < 4; ++k) {
            float r = accR[ii][k];
            r += __shfl_xor(r, 16); r += __shfl_xor(r, 32);
            accR[ii][k] = r;
            float q = accI[ii][k];
            q += __shfl_xor(q, 16); q += __shfl_xor(q, 32);
            accI[ii][k] = q;
        }
    // lane (su,j) stores ky = kq*4+su, i = 4j..4j+3 (static indices only)
    float selR[4], selI[4];
#pragma unroll
    for (int ii = 0; ii < 4; ++ii) {
        selR[ii] = su == 0 ? accR[ii][0] : su == 1 ? accR[ii][1]
                 : su == 2 ? accR[ii][2] : accR[ii][3];
        selI[ii] = su == 0 ? accI[ii][0] : su == 1 ? accI[ii][1]
                 : su == 2 ? accI[ii][2] : accI[ii][3];
    }
    int ky = kq * 4 + su;
    float* Tf = T + (((size_t)(b * 16 + ky) * 256 + m) * 64 + 4 * j) * 2;
    *(float4*)Tf       = make_float4(selR[0], selI[0], selR[1], selI[1]);
    *(float4*)(Tf + 4) = make_float4(selR[2], selI[2], selR[3], selI[3]);
}

// Stage B v4: block = (b, ky), 512 threads / 8 waves = (oc = kx-octet) x
// (smh = m-half). Wave: 8 kx x 128 m; full 256 m covered inside the block.
// Twiddles are wave-uniform VMEM float4 loads (no SMEM in loop).
// LDS pair-reduce smh=1 into smh=0, then store X.
__global__ __launch_bounds__(512) void stageB(const float* __restrict__ T,
                                              const float* __restrict__ twF,
                                              float* __restrict__ X) {
    __shared__ float red[4 * 8 * 64 * 2];  // 16 KiB [oc][kk][i][2]
    int bid = blockIdx.x;            // b*16 + ky
    int b = bid >> 4;
    int ky = bid & 15;
    int t = threadIdx.x, i = t & 63;
    int w = t >> 6, oc = w & 3, smh = w >> 2;
    int m0 = smh * 128;
    const float2* Tp = (const float2*)T + (size_t)(b * 16 + ky) * 16384 + i;
    const float* twp = twF + oc * 4096;
    float aR[8], aI[8];
#pragma unroll
    for (int k = 0; k < 8; ++k) { aR[k] = 0.f; aI[k] = 0.f; }
#pragma unroll 4
    for (int mm = 0; mm < 128; ++mm) {
        int m = m0 + mm;
        float2 tv = Tp[(size_t)m * 64];
        const float* tp = twp + m * 16;
        float4 w0 = *(const float4*)(tp);
        float4 w1 = *(const float4*)(tp + 4);
        float4 w2 = *(const float4*)(tp + 8);
        float4 w3 = *(const float4*)(tp + 12);
#define CMUL(K, C, S)                                             \
        aR[K] = fmaf(tv.x, C, fmaf(-tv.y, S, aR[K]));             \
        aI[K] = fmaf(tv.x, S, fmaf( tv.y, C, aI[K]));
        CMUL(0, w0.x, w0.y) CMUL(1, w0.z, w0.w)
        CMUL(2, w1.x, w1.y) CMUL(3, w1.z, w1.w)
        CMUL(4, w2.x, w2.y) CMUL(5, w2.z, w2.w)
        CMUL(6, w3.x, w3.y) CMUL(7, w3.z, w3.w)
#undef CMUL
    }
    float2* rp = (float2*)red + (oc * 8) * 64 + i;
    if (smh == 1) {
#pragma unroll
        for (int k = 0; k < 8; ++k) rp[k * 64] = make_float2(aR[k], aI[k]);
    }
    __syncthreads();
    if (smh == 0) {
        float2* Xb = (float2*)X;
        size_t base = ((size_t)(b * 16 + ky) * 32 + oc * 8) * 64 + i;
#pragma unroll
        for (int k = 0; k < 8; ++k) {
            float2 p = rp[k * 64];
            Xb[base + (size_t)k * 64] = make_float2(aR[k] + p.x, aI[k] + p.y);
        }
    }
}

// Stage C: per (kx,ky): Y[b,o'] = sum_i X[b,i]*W[i,o'];  Y2[b,o] = sum_o' Y[b,o']*Wf[o',o]
__global__ __launch_bounds__(256) void stageC(const float* __restrict__ Xg,
                                              const float* __restrict__ w1,
                                              const float* __restrict__ w2,
                                              const float* __restrict__ Wf,
                                              float* __restrict__ Y2) {
    __shared__ float Ws[64 * 64 * 2];  // 32 KiB [i][o][2]
    __shared__ float Xs[8 * 64 * 2];   //  4 KiB [b][i][2]
    __shared__ float Ys[8 * 64 * 2];   //  4 KiB [b][o][2]
    __shared__ float Wfs[64 * 64];     // 16 KiB
    int bid = blockIdx.x;              // ky*32 + kx
    int kx = bid & 31, ky = bid >> 5;
    int t = threadIdx.x;
    const float* wsrc = (kx < 16) ? w1 : w2;
    int xx = kx & 15;
#pragma unroll
    for (int q = 0; q < 16; ++q) {
        int p = t + q * 256;
        int ii = p >> 6, oo = p & 63;
        float2 wv = *(const float2*)(wsrc + ((size_t)(ii * 64 + oo) * 256 + xx * 16 + ky) * 2);
        ((float2*)Ws)[ii * 64 + oo] = wv;
    }
#pragma unroll
    for (int q = 0; q < 2; ++q) {
        int p = t + q * 256;
        int bb = p >> 6, ii = p & 63;
        ((float2*)Xs)[bb * 64 + ii] =
            ((const float2*)Xg)[((size_t)(bb * 16 + ky) * 32 + kx) * 64 + ii];
    }
#pragma unroll
    for (int q = 0; q < 16; ++q) Wfs[t + q * 256] = Wf[t + q * 256];
    __syncthreads();
    int o = t & 63, bg = t >> 6;
    float yr0 = 0, yi0 = 0, yr1 = 0, yi1 = 0;
    for (int ii = 0; ii < 64; ++ii) {
        float2 w = ((float2*)Ws)[ii * 64 + o];
        float2 xa = ((float2*)Xs)[bg * 64 + ii];
        float2 xb = ((float2*)Xs)[(bg + 4) * 64 + ii];
        yr0 = fmaf(xa.x, w.x, fmaf(-xa.y, w.y, yr0));
        yi0 = fmaf(xa.x, w.y, fmaf( xa.y, w.x, yi0));
        yr1 = fmaf(xb.x, w.x, fmaf(-xb.y, w.y, yr1));
        yi1 = fmaf(xb.x, w.y, fmaf( xb.y, w.x, yi1));
    }
    ((float2*)Ys)[bg * 64 + o] = make_float2(yr0, yi0);
    ((float2*)Ys)[(bg + 4) * 64 + o] = make_float2(yr1, yi1);
    __syncthreads();
    float zr0 = 0, zi0 = 0, zr1 = 0, zi1 = 0;
    for (int op = 0; op < 64; ++op) {
        float wf = Wfs[op * 64 + o];
        float2 ya = ((float2*)Ys)[bg * 64 + op];
        float2 yb = ((float2*)Ys)[(bg + 4) * 64 + op];
        zr0 = fmaf(ya.x, wf, zr0); zi0 = fmaf(ya.y, wf, zi0);
        zr1 = fmaf(yb.x, wf, zr1); zi1 = fmaf(yb.y, wf, zi1);
    }
    float2* Yb = (float2*)Y2;
    Yb[((size_t)(bg * 32 + kx) * 16 + ky) * 64 + o] = make_float2(zr0, zi0);
    Yb[((size_t)((bg + 4) * 32 + kx) * 16 + ky) * 64 + o] = make_float2(zr1, zi1);
}

// Stage D: G[m,ky,o] = sum_kx Y2[kx,ky,o] * twI[kx,m]
__global__ __launch_bounds__(512) void stageD(const float* __restrict__ Y2,
                                              const float* __restrict__ twI,
                                              float* __restrict__ G) {
    __shared__ float Ysl[16 * 64 * 2];  // 8 KiB slice [ky][o][2]
    int bid = blockIdx.x;               // b*32 + mg
    int b = bid >> 5, mg = bid & 31;
    int t = threadIdx.x, o = t & 63, ml = t >> 6;   // 8 m per block
    int m = mg * 8 + ml;
    float gr[16], gi[16];
#pragma unroll
    for (int k = 0; k < 16; ++k) { gr[k] = 0.f; gi[k] = 0.f; }
    for (int kx = 0; kx < 32; ++kx) {
        __syncthreads();
        const float2* src = (const float2*)Y2 + (size_t)(b * 32 + kx) * 1024;
#pragma unroll
        for (int qq = 0; qq < 2; ++qq) ((float2*)Ysl)[t + qq * 512] = src[t + qq * 512];
        __syncthreads();
        float2 cd = *(const float2*)(twI + (size_t)(kx * 256 + m) * 2);
        float c = cd.x, d = cd.y;
#pragma unroll
        for (int ky = 0; ky < 16; ++ky) {
            float2 yv = ((float2*)Ysl)[ky * 64 + o];
            gr[ky] = fmaf(yv.x, c, fmaf(-yv.y, d, gr[ky]));
            gi[ky] = fmaf(yv.x, d, fmaf( yv.y, c, gi[ky]));
        }
    }
    float2* Gb = (float2*)G;
#pragma unroll
    for (int ky = 0; ky < 16; ++ky)
        Gb[((size_t)(b * 256 + m) * 16 + ky) * 64 + o] = make_float2(gr[ky], gi[ky]);
}

// Stage E: per (b,m): out[n,o] = relu( sum_f Bas[f,n]*H[f,o] + lin_b[o] )
__global__ __launch_bounds__(256) void stageE(const float* __restrict__ G,
                                              const float* __restrict__ tabE,
                                              const float* __restrict__ lin_b,
                                              float* __restrict__ out) {
    __shared__ float Bs[32 * 256];  // 32 KiB [f][n]
    __shared__ float Hs[32 * 64];   //  8 KiB [f][o]
    int bid = blockIdx.x;           // b*256 + m
    int t = threadIdx.x;
    const float4* tE4 = (const float4*)tabE;
#pragma unroll
    for (int q = 0; q < 8; ++q) ((float4*)Bs)[t + q * 256] = tE4[t + q * 256];
    const float2* Gp = (const float2*)G + (size_t)bid * 1024;
#pragma unroll
    for (int q = 0; q < 4; ++q) {
        int p = t + q * 256;
        int ky = p >> 6, o = p & 63;
        float2 g = Gp[p];
        Hs[(2 * ky) * 64 + o] = g.x;
        Hs[(2 * ky + 1) * 64 + o] = g.y;
    }
    __syncthreads();
    int o4 = (t & 15) * 4, n0 = (t >> 4) * 16;
    float acc[16][4];
#pragma unroll
    for (int j = 0; j < 16; ++j) { acc[j][0] = acc[j][1] = acc[j][2] = acc[j][3] = 0.f; }
    for (int f = 0; f < 32; ++f) {
        float4 h = *(const float4*)(Hs + f * 64 + o4);
        const float* bp = Bs + f * 256 + n0;
        float4 a0 = *(const float4*)(bp);
        float4 a1 = *(const float4*)(bp + 4);
        float4 a2 = *(const float4*)(bp + 8);
        float4 a3 = *(const float4*)(bp + 12);
        float av[16] = {a0.x, a0.y, a0.z, a0.w, a1.x, a1.y, a1.z, a1.w,
                        a2.x, a2.y, a2.z, a2.w, a3.x, a3.y, a3.z, a3.w};
#pragma unroll
        for (int j = 0; j < 16; ++j) {
            acc[j][0] = fmaf(av[j], h.x, acc[j][0]);
            acc[j][1] = fmaf(av[j], h.y, acc[j][1]);
            acc[j][2] = fmaf(av[j], h.z, acc[j][2]);
            acc[j][3] = fmaf(av[j], h.w, acc[j][3]);
        }
    }
    float4 bias = *(const float4*)(lin_b + o4);
    float* outp = out + (size_t)bid * 256 * 64;
#pragma unroll
    for (int j = 0; j < 16; ++j) {
        int n = n0 + j;
        float4 r;
        r.x = fmaxf(acc[j][0] + bias.x, 0.f);
        r.y = fmaxf(acc[j][1] + bias.y, 0.f);
        r.z = fmaxf(acc[j][2] + bias.z, 0.f);
        r.w = fmaxf(acc[j][3] + bias.w, 0.f);
        *(float4*)(outp + (size_t)n * 64 + o4) = r;
    }
}

extern "C" void kernel_launch(void* const* d_in, const int* in_sizes, int n_in,
                              void* d_out, int out_size, void* d_ws, size_t ws_size,
                              hipStream_t stream) {
    const float* x     = (const float*)d_in[0];
    const float* w1    = (const float*)d_in[1];
    const float* w2    = (const float*)d_in[2];
    const float* lin_w = (const float*)d_in[3];
    const float* lin_b = (const float*)d_in[4];
    float* ws  = (float*)d_ws;
    float* out = (float*)d_out;

    float* T  = ws + TOFF;
    float* X  = ws + XOFF;
    float* Y2 = ws + YOFF;
    float* G  = ws + GOFF;

    setup_tables<<<128, 256, 0, stream>>>(lin_w, ws);
    stageA<<<2048, 256, 0, stream>>>(x, ws, T);
    stageB<<<128, 512, 0, stream>>>(T, ws + 8192, X);
    stageC<<<512, 256, 0, stream>>>(X, w1, w2, ws + 49152, Y2);
    stageD<<<256, 512, 0, stream>>>(Y2, ws + 24576, G);
    stageE<<<2048, 256, 0, stream>>>(G, ws + 40960, lin_b, out);
}

// Round 8
// 156.811 us; speedup vs baseline: 1.2670x; 1.2670x over previous
//
#include <hip/hip_runtime.h>
#include <hip/hip_bf16.h>
#include <math.h>

// Problem constants: B=8, M=256, N=256, I=64, O=64, NM=16
// Workspace float layout:
//   [0)      tabA  [n=256][ky=16][2]        8192   forward-n twiddles (cos,-sin)
//   [8192)   twF   [g=8][m=256][kl=4][2]   16384   forward-m twiddles (cos,-sin)
//   [24576)  twI   [kx=32][m=256][2]       16384   inverse-m twiddles (cos,+sin)/256
//   [40960)  tabE  [f=32][n=256]            8192   inverse-n basis (scaled cos / -sin)
//   [49152)  Wf    [o'=64][o=64]            4096   I + lin_w
//   [65536)  T     [b=8][ky=16][m=256][i=64][2]   = 4194304
//   [+T]     X     [b=8][ky=16][kx=32][i=64][2]   =  524288
//   [+X]     Y2    [b=8][kx=32][ky=16][o=64][2]   =  524288
//   [+Y2]    G     [b=8][m=256][ky=16][o=64][2]   = 4194304

#define TOFF  65536
#define XOFF  (TOFF + 4194304)
#define YOFF  (XOFF + 524288)
#define GOFF  (YOFF + 524288)

__global__ __launch_bounds__(256) void setup_tables(const float* __restrict__ lin_w,
                                                    float* __restrict__ ws) {
    int j = blockIdx.x * 256 + threadIdx.x;
    const float ANG = 0.024543692606170259f; // 2*pi/256
    if (j < 4096) {                       // tabA [n][ky][2]
        int n = j >> 4, ky = j & 15;
        int a = (n * ky) & 255;
        float s, c; sincosf(ANG * (float)a, &s, &c);
        float* p = ws + n * 32 + ky * 2;
        p[0] = c; p[1] = -s;
    } else if (j < 12288) {               // twF [g=8][m][kl=4][2]
        int e = j - 4096; int m = e >> 5, kx = e & 31;
        int kxe = kx + (kx < 16 ? 0 : 224);   // 0..15, 240..255
        int a = (m * kxe) & 255;
        float s, c; sincosf(ANG * (float)a, &s, &c);
        int g = kx >> 2, kl = kx & 3;
        float* p = ws + 8192 + g * 2048 + m * 8 + kl * 2;
        p[0] = c; p[1] = -s;
    } else if (j < 20480) {               // twI
        int e = j - 12288; int kx = e >> 8, m = e & 255;
        int kxe = kx + (kx < 16 ? 0 : 224);
        int a = (kxe * m) & 255;
        float s, c; sincosf(ANG * (float)a, &s, &c);
        float* p = ws + 24576 + (kx * 256 + m) * 2;
        p[0] = c * (1.0f / 256.0f);
        p[1] = s * (1.0f / 256.0f);
    } else if (j < 28672) {               // tabE
        int e = j - 20480; int f = e >> 8, n = e & 255;
        int ky = f >> 1, h = f & 1;
        int a = (ky * n) & 255;
        float s, c; sincosf(ANG * (float)a, &s, &c);
        float scale = (ky == 0 ? 1.0f : 2.0f) * (1.0f / 256.0f);
        ws[40960 + f * 256 + n] = h ? (-scale * s) : (scale * c);
    } else if (j < 32768) {               // Wf = I + lin_w
        int e = j - 28672;
        int op = e >> 6, o = e & 63;
        ws[49152 + e] = lin_w[e] + ((op == o) ? 1.0f : 0.0f);
    }
}

// Stage A v9: block = (b, m-pair); 4 waves = n-quarters; lane = i.
// Twiddles staged ONCE into LDS (32 KiB) -> inner-loop twiddle reads are
// ds_read_b128 broadcasts (lgkmcnt is DS-ONLY -> in-order -> compiler emits
// counted waits, m97-style). x via direct global dwords (vmcnt only), read
// exactly once grid-wide. m-pair doubles FMA per twiddle byte: per n,
// 2 VMEM + 8 DS feed 64 FMA instrs. LDS reused as the cross-wave reduce buf.
__global__ __launch_bounds__(256) void stageA(const float* __restrict__ x,
                                              const float* __restrict__ tabA,
                                              float* __restrict__ T) {
    __shared__ float sm[8192];  // 32 KiB: twiddles [n][ky][2], then reduce buf
    int bid = blockIdx.x;       // b*128 + mp ; m0 = mp*2
    int b = bid >> 7, mp = bid & 127;
    int m0 = mp * 2;
    int t = threadIdx.x;
    int i = t & 63, w = t >> 6;
    {
        const float4* src = (const float4*)tabA;
        float4* dst = (float4*)sm;
#pragma unroll
        for (int q = 0; q < 8; ++q) dst[t + q * 256] = src[t + q * 256];
    }
    __syncthreads();

    const float* xp0 = x + (((size_t)(b * 256 + m0) * 256) + w * 64) * 64 + i;
    const float* xp1 = xp0 + 16384;   // m0+1
    float aR[2][16], aI[2][16];
#pragma unroll
    for (int mm = 0; mm < 2; ++mm)
#pragma unroll
        for (int k = 0; k < 16; ++k) { aR[mm][k] = 0.f; aI[mm][k] = 0.f; }

    const float* twb = sm + w * 64 * 32;   // this wave's n-quarter rows
#pragma unroll 2
    for (int nn = 0; nn < 64; ++nn) {
        float x0 = xp0[(size_t)nn * 64];
        float x1 = xp1[(size_t)nn * 64];
        const float* tp = twb + nn * 32;
#pragma unroll
        for (int q = 0; q < 8; ++q) {
            float4 tv = *(const float4*)(tp + q * 4);   // ky=2q, 2q+1 (c,-s,c,-s)
            int k0 = 2 * q, k1 = 2 * q + 1;
            aR[0][k0] = fmaf(tv.x, x0, aR[0][k0]); aI[0][k0] = fmaf(tv.y, x0, aI[0][k0]);
            aR[1][k0] = fmaf(tv.x, x1, aR[1][k0]); aI[1][k0] = fmaf(tv.y, x1, aI[1][k0]);
            aR[0][k1] = fmaf(tv.z, x0, aR[0][k1]); aI[0][k1] = fmaf(tv.w, x0, aI[0][k1]);
            aR[1][k1] = fmaf(tv.z, x1, aR[1][k1]); aI[1][k1] = fmaf(tv.w, x1, aI[1][k1]);
        }
    }

    // cross-wave reduce: layout [slot][reg r=0..63][i]; lane-contiguous (no conflicts)
    __syncthreads();   // twiddle reads done; sm reusable
    if (w == 1 || w == 3) {
        float* rp = sm + ((w == 1) ? 0 : 4096) + i;
#pragma unroll
        for (int mm = 0; mm < 2; ++mm)
#pragma unroll
            for (int k = 0; k < 16; ++k) {
                rp[(mm * 32 + 2 * k) * 64]     = aR[mm][k];
                rp[(mm * 32 + 2 * k + 1) * 64] = aI[mm][k];
            }
    }
    __syncthreads();
    if (w == 0 || w == 2) {
        const float* rp = sm + ((w == 0) ? 0 : 4096) + i;
#pragma unroll
        for (int mm = 0; mm < 2; ++mm)
#pragma unroll
            for (int k = 0; k < 16; ++k) {
                aR[mm][k] += rp[(mm * 32 + 2 * k) * 64];
                aI[mm][k] += rp[(mm * 32 + 2 * k + 1) * 64];
            }
    }
    __syncthreads();
    if (w == 2) {
        float* rp = sm + i;
#pragma unroll
        for (int mm = 0; mm < 2; ++mm)
#pragma unroll
            for (int k = 0; k < 16; ++k) {
                rp[(mm * 32 + 2 * k) * 64]     = aR[mm][k];
                rp[(mm * 32 + 2 * k + 1) * 64] = aI[mm][k];
            }
    }
    __syncthreads();
    if (w == 0) {
        const float* rp = sm + i;
        float2* Tb = (float2*)T;
#pragma unroll
        for (int mm = 0; mm < 2; ++mm)
#pragma unroll
            for (int k = 0; k < 16; ++k) {
                float r = aR[mm][k] + rp[(mm * 32 + 2 * k) * 64];
                float q = aI[mm][k] + rp[(mm * 32 + 2 * k + 1) * 64];
                Tb[((size_t)(b * 16 + k) * 256 + (m0 + mm)) * 64 + i] = make_float2(r, q);
            }
    }
}

// Stage B (R4 v2, proven): block = (b, ky, half) of 512 threads / 8 waves.
// Wave w: kx quad Q = half*4 + (w&3), m-half h = w>>2 covering 128 m.
// 8 twiddle floats per m (s_load_dwordx8); pair-reduce h=1 into h=0 via LDS.
__global__ __launch_bounds__(512) void stageB(const float* __restrict__ T,
                                              const float* __restrict__ twF,
                                              float* __restrict__ X) {
    __shared__ float red[4 * 4 * 64 * 2];  // 8 KiB [q][j][i][2]
    int bid = blockIdx.x;            // b*32 + ky*2 + half
    int b = bid >> 5;
    int ky = (bid >> 1) & 15;
    int half = bid & 1;
    int t = threadIdx.x, i = t & 63;
    int q = (t >> 6) & 3, h = t >> 8;
    int Q = half * 4 + q;
    const float2* Tp = (const float2*)T + (size_t)(b * 16 + ky) * 256 * 64 + i;
    const float* tw = twF + __builtin_amdgcn_readfirstlane(Q * 2048);
    float r0 = 0, r1 = 0, r2 = 0, r3 = 0;
    float s0 = 0, s1 = 0, s2 = 0, s3 = 0;
    int m0 = h * 128;
#pragma unroll 4
    for (int mm = 0; mm < 128; ++mm) {
        int m = m0 + mm;
        float2 tv = Tp[(size_t)m * 64];
        const float* tp = tw + m * 8;
        r0 = fmaf(tv.x, tp[0], fmaf(-tv.y, tp[1], r0));
        s0 = fmaf(tv.x, tp[1], fmaf( tv.y, tp[0], s0));
        r1 = fmaf(tv.x, tp[2], fmaf(-tv.y, tp[3], r1));
        s1 = fmaf(tv.x, tp[3], fmaf( tv.y, tp[2], s1));
        r2 = fmaf(tv.x, tp[4], fmaf(-tv.y, tp[5], r2));
        s2 = fmaf(tv.x, tp[5], fmaf( tv.y, tp[4], s2));
        r3 = fmaf(tv.x, tp[6], fmaf(-tv.y, tp[7], r3));
        s3 = fmaf(tv.x, tp[7], fmaf( tv.y, tp[6], s3));
    }
    float2* rp = (float2*)red + (q * 4) * 64 + i;
    if (h == 1) {
        rp[0 * 64] = make_float2(r0, s0);
        rp[1 * 64] = make_float2(r1, s1);
        rp[2 * 64] = make_float2(r2, s2);
        rp[3 * 64] = make_float2(r3, s3);
    }
    __syncthreads();
    if (h == 0) {
        float2 p0 = rp[0 * 64], p1 = rp[1 * 64], p2 = rp[2 * 64], p3 = rp[3 * 64];
        r0 += p0.x; s0 += p0.y; r1 += p1.x; s1 += p1.y;
        r2 += p2.x; s2 += p2.y; r3 += p3.x; s3 += p3.y;
        int kx0 = Q * 4;
        float2* Xb = (float2*)X;
        size_t base = ((size_t)(b * 16 + ky) * 32 + kx0) * 64 + i;
        Xb[base + 0 * 64] = make_float2(r0, s0);
        Xb[base + 1 * 64] = make_float2(r1, s1);
        Xb[base + 2 * 64] = make_float2(r2, s2);
        Xb[base + 3 * 64] = make_float2(r3, s3);
    }
}

// Stage C: per (kx,ky): Y[b,o'] = sum_i X[b,i]*W[i,o'];  Y2[b,o] = sum_o' Y[b,o']*Wf[o',o]
__global__ __launch_bounds__(256) void stageC(const float* __restrict__ Xg,
                                              const float* __restrict__ w1,
                                              const float* __restrict__ w2,
                                              const float* __restrict__ Wf,
                                              float* __restrict__ Y2) {
    __shared__ float Ws[64 * 64 * 2];  // 32 KiB [i][o][2]
    __shared__ float Xs[8 * 64 * 2];   //  4 KiB [b][i][2]
    __shared__ float Ys[8 * 64 * 2];   //  4 KiB [b][o][2]
    __shared__ float Wfs[64 * 64];     // 16 KiB
    int bid = blockIdx.x;              // ky*32 + kx
    int kx = bid & 31, ky = bid >> 5;
    int t = threadIdx.x;
    const float* wsrc = (kx < 16) ? w1 : w2;
    int xx = kx & 15;
#pragma unroll
    for (int q = 0; q < 16; ++q) {
        int p = t + q * 256;
        int ii = p >> 6, oo = p & 63;
        float2 wv = *(const float2*)(wsrc + ((size_t)(ii * 64 + oo) * 256 + xx * 16 + ky) * 2);
        ((float2*)Ws)[ii * 64 + oo] = wv;
    }
#pragma unroll
    for (int q = 0; q < 2; ++q) {
        int p = t + q * 256;
        int bb = p >> 6, ii = p & 63;
        ((float2*)Xs)[bb * 64 + ii] =
            ((const float2*)Xg)[((size_t)(bb * 16 + ky) * 32 + kx) * 64 + ii];
    }
#pragma unroll
    for (int q = 0; q < 16; ++q) Wfs[t + q * 256] = Wf[t + q * 256];
    __syncthreads();
    int o = t & 63, bg = t >> 6;
    float yr0 = 0, yi0 = 0, yr1 = 0, yi1 = 0;
    for (int ii = 0; ii < 64; ++ii) {
        float2 w = ((float2*)Ws)[ii * 64 + o];
        float2 xa = ((float2*)Xs)[bg * 64 + ii];
        float2 xb = ((float2*)Xs)[(bg + 4) * 64 + ii];
        yr0 = fmaf(xa.x, w.x, fmaf(-xa.y, w.y, yr0));
        yi0 = fmaf(xa.x, w.y, fmaf( xa.y, w.x, yi0));
        yr1 = fmaf(xb.x, w.x, fmaf(-xb.y, w.y, yr1));
        yi1 = fmaf(xb.x, w.y, fmaf( xb.y, w.x, yi1));
    }
    ((float2*)Ys)[bg * 64 + o] = make_float2(yr0, yi0);
    ((float2*)Ys)[(bg + 4) * 64 + o] = make_float2(yr1, yi1);
    __syncthreads();
    float zr0 = 0, zi0 = 0, zr1 = 0, zi1 = 0;
    for (int op = 0; op < 64; ++op) {
        float wf = Wfs[op * 64 + o];
        float2 ya = ((float2*)Ys)[bg * 64 + op];
        float2 yb = ((float2*)Ys)[(bg + 4) * 64 + op];
        zr0 = fmaf(ya.x, wf, zr0); zi0 = fmaf(ya.y, wf, zi0);
        zr1 = fmaf(yb.x, wf, zr1); zi1 = fmaf(yb.y, wf, zi1);
    }
    float2* Yb = (float2*)Y2;
    Yb[((size_t)(bg * 32 + kx) * 16 + ky) * 64 + o] = make_float2(zr0, zi0);
    Yb[((size_t)((bg + 4) * 32 + kx) * 16 + ky) * 64 + o] = make_float2(zr1, zi1);
}

// Stage D: G[m,ky,o] = sum_kx Y2[kx,ky,o] * twI[kx,m]
__global__ __launch_bounds__(512) void stageD(const float* __restrict__ Y2,
                                              const float* __restrict__ twI,
                                              float* __restrict__ G) {
    __shared__ float Ysl[16 * 64 * 2];  // 8 KiB slice [ky][o][2]
    int bid = blockIdx.x;               // b*32 + mg
    int b = bid >> 5, mg = bid & 31;
    int t = threadIdx.x, o = t & 63, ml = t >> 6;   // 8 m per block
    int m = mg * 8 + ml;
    float gr[16], gi[16];
#pragma unroll
    for (int k = 0; k < 16; ++k) { gr[k] = 0.f; gi[k] = 0.f; }
    for (int kx = 0; kx < 32; ++kx) {
        __syncthreads();
        const float2* src = (const float2*)Y2 + (size_t)(b * 32 + kx) * 1024;
#pragma unroll
        for (int qq = 0; qq < 2; ++qq) ((float2*)Ysl)[t + qq * 512] = src[t + qq * 512];
        __syncthreads();
        float2 cd = *(const float2*)(twI + (size_t)(kx * 256 + m) * 2);
        float c = cd.x, d = cd.y;
#pragma unroll
        for (int ky = 0; ky < 16; ++ky) {
            float2 yv = ((float2*)Ysl)[ky * 64 + o];
            gr[ky] = fmaf(yv.x, c, fmaf(-yv.y, d, gr[ky]));
            gi[ky] = fmaf(yv.x, d, fmaf( yv.y, c, gi[ky]));
        }
    }
    float2* Gb = (float2*)G;
#pragma unroll
    for (int ky = 0; ky < 16; ++ky)
        Gb[((size_t)(b * 256 + m) * 16 + ky) * 64 + o] = make_float2(gr[ky], gi[ky]);
}

// Stage E: per (b,m): out[n,o] = relu( sum_f Bas[f,n]*H[f,o] + lin_b[o] )
__global__ __launch_bounds__(256) void stageE(const float* __restrict__ G,
                                              const float* __restrict__ tabE,
                                              const float* __restrict__ lin_b,
                                              float* __restrict__ out) {
    __shared__ float Bs[32 * 256];  // 32 KiB [f][n]
    __shared__ float Hs[32 * 64];   //  8 KiB [f][o]
    int bid = blockIdx.x;           // b*256 + m
    int t = threadIdx.x;
    const float4* tE4 = (const float4*)tabE;
#pragma unroll
    for (int q = 0; q < 8; ++q) ((float4*)Bs)[t + q * 256] = tE4[t + q * 256];
    const float2* Gp = (const float2*)G + (size_t)bid * 1024;
#pragma unroll
    for (int q = 0; q < 4; ++q) {
        int p = t + q * 256;
        int ky = p >> 6, o = p & 63;
        float2 g = Gp[p];
        Hs[(2 * ky) * 64 + o] = g.x;
        Hs[(2 * ky + 1) * 64 + o] = g.y;
    }
    __syncthreads();
    int o4 = (t & 15) * 4, n0 = (t >> 4) * 16;
    float acc[16][4];
#pragma unroll
    for (int j = 0; j < 16; ++j) { acc[j][0] = acc[j][1] = acc[j][2] = acc[j][3] = 0.f; }
    for (int f = 0; f < 32; ++f) {
        float4 h = *(const float4*)(Hs + f * 64 + o4);
        const float* bp = Bs + f * 256 + n0;
        float4 a0 = *(const float4*)(bp);
        float4 a1 = *(const float4*)(bp + 4);
        float4 a2 = *(const float4*)(bp + 8);
        float4 a3 = *(const float4*)(bp + 12);
        float av[16] = {a0.x, a0.y, a0.z, a0.w, a1.x, a1.y, a1.z, a1.w,
                        a2.x, a2.y, a2.z, a2.w, a3.x, a3.y, a3.z, a3.w};
#pragma unroll
        for (int j = 0; j < 16; ++j) {
            acc[j][0] = fmaf(av[j], h.x, acc[j][0]);
            acc[j][1] = fmaf(av[j], h.y, acc[j][1]);
            acc[j][2] = fmaf(av[j], h.z, acc[j][2]);
            acc[j][3] = fmaf(av[j], h.w, acc[j][3]);
        }
    }
    float4 bias = *(const float4*)(lin_b + o4);
    float* outp = out + (size_t)bid * 256 * 64;
#pragma unroll
    for (int j = 0; j < 16; ++j) {
        int n = n0 + j;
        float4 r;
        r.x = fmaxf(acc[j][0] + bias.x, 0.f);
        r.y = fmaxf(acc[j][1] + bias.y, 0.f);
        r.z = fmaxf(acc[j][2] + bias.z, 0.f);
        r.w = fmaxf(acc[j][3] + bias.w, 0.f);
        *(float4*)(outp + (size_t)n * 64 + o4) = r;
    }
}

extern "C" void kernel_launch(void* const* d_in, const int* in_sizes, int n_in,
                              void* d_out, int out_size, void* d_ws, size_t ws_size,
                              hipStream_t stream) {
    const float* x     = (const float*)d_in[0];
    const float* w1    = (const float*)d_in[1];
    const float* w2    = (const float*)d_in[2];
    const float* lin_w = (const float*)d_in[3];
    const float* lin_b = (const float*)d_in[4];
    float* ws  = (float*)d_ws;
    float* out = (float*)d_out;

    float* T  = ws + TOFF;
    float* X  = ws + XOFF;
    float* Y2 = ws + YOFF;
    float* G  = ws + GOFF;

    setup_tables<<<128, 256, 0, stream>>>(lin_w, ws);
    stageA<<<1024, 256, 0, stream>>>(x, ws, T);
    stageB<<<256, 512, 0, stream>>>(T, ws + 8192, X);
    stageC<<<512, 256, 0, stream>>>(X, w1, w2, ws + 49152, Y2);
    stageD<<<256, 512, 0, stream>>>(Y2, ws + 24576, G);
    stageE<<<2048, 256, 0, stream>>>(G, ws + 40960, lin_b, out);
}